// Round 1
// baseline (610.860 us; speedup 1.0000x reference)
//
#include <hip/hip_runtime.h>

// Cost volume: left,right [B=2, C=32, H=128, W=256] fp32, max_disp D=32.
// out [B, 2C, D, H, W]:
//   c2 <  C: out = (w+d < W)  ? left [b,c2,  h, w+d] : 0
//   c2 >= C: out = (w-d >= 0) ? right[b,c2-C,h, w-d] : 0
// Pure store-BW-bound: 512 MiB out, 16 MiB in (cached, 32x reuse).

__global__ __launch_bounds__(256) void costvol_kernel(
        const float* __restrict__ left,
        const float* __restrict__ right,
        float* __restrict__ out) {
    constexpr int W = 256, H = 128, D = 32, C = 32;
    (void)H; (void)D;

    unsigned n = blockIdx.x * 256u + threadIdx.x;   // float4 index
    // flat float index = n*4 = w + W*(h + H*(d + D*(c2 + 2C*b)))
    unsigned w  = (n & 63u) << 2;      // W/4 = 64 float4s per row
    unsigned r  = n >> 6;
    unsigned h  = r & 127u; r >>= 7;   // H = 128
    unsigned d  = r & 31u;  r >>= 5;   // D = 32
    unsigned c2 = r & 63u;  r >>= 6;   // 2C = 64
    unsigned b  = r;                   // B = 2

    float4 v;
    if (c2 < C) {
        // one wave = 64 threads = one full W-row -> branch is wave-uniform
        const float* row = left + (size_t)(((b * C + c2) * (unsigned)H + h)) * W;
        int base = (int)(w + d);
        v.x = (base + 0 < W) ? row[base + 0] : 0.f;
        v.y = (base + 1 < W) ? row[base + 1] : 0.f;
        v.z = (base + 2 < W) ? row[base + 2] : 0.f;
        v.w = (base + 3 < W) ? row[base + 3] : 0.f;
    } else {
        const float* row = right + (size_t)(((b * C + (c2 - C)) * (unsigned)H + h)) * W;
        int base = (int)w - (int)d;
        v.x = (base + 0 >= 0) ? row[base + 0] : 0.f;
        v.y = (base + 1 >= 0) ? row[base + 1] : 0.f;
        v.z = (base + 2 >= 0) ? row[base + 2] : 0.f;
        v.w = (base + 3 >= 0) ? row[base + 3] : 0.f;
    }
    reinterpret_cast<float4*>(out)[n] = v;
}

extern "C" void kernel_launch(void* const* d_in, const int* in_sizes, int n_in,
                              void* d_out, int out_size, void* d_ws, size_t ws_size,
                              hipStream_t stream) {
    const float* left  = (const float*)d_in[0];
    const float* right = (const float*)d_in[1];
    float* out = (float*)d_out;

    // out_size = 2*64*32*128*256 = 134,217,728 floats -> 33,554,432 float4s
    const unsigned n4 = (unsigned)(out_size / 4);
    const unsigned blocks = (n4 + 255u) / 256u;   // 131,072 blocks
    costvol_kernel<<<blocks, 256, 0, stream>>>(left, right, out);
}